// Round 2
// baseline (579.853 us; speedup 1.0000x reference)
//
#include <hip/hip_runtime.h>
#include <hip/hip_cooperative_groups.h>

// SocialPoolingLayer: fused edge-MLP (relu(pair@W1+b1)@W2+b2, sigmoid gate, elemwise
// product) + scatter-mean by src node.
// Round 11 (aux-consolidation round): R0/R1 both show dur_us - edge_mlp ~= 157us
// constant -- the 5-dispatch aux chain (memset+prep+scan+scatter) is now 2/3 of total.
// Physics says its WORK is ~30-50us, so most of the gap is dispatch/drain overhead.
// Fix: ONE cooperative kernel (phases: zero-cnt | prep-branches | scan | scatter with
// cg grid syncs), grid-stride everywhere, grid sized via occupancy query (static).
// Falls back to the proven R10 5-dispatch path if cooperative launch is rejected.
// Main kernel edge_mlp_mfma is byte-identical to R10 (isolate the structural change).

namespace cg = cooperative_groups;

typedef unsigned short ushort_t;
typedef __attribute__((ext_vector_type(8))) short     bf16x8;   // 8 bf16 = 4 VGPRs
typedef __attribute__((ext_vector_type(8))) unsigned short u16x8;
typedef __attribute__((ext_vector_type(4))) float     f32x4;

constexpr int D        = 64;
constexpr int TILE     = 64;     // edges per block (4 waves x 16 edges)
constexpr int BLOCK    = 256;
constexpr int NFRAG    = 32;     // 16 (W1) + 8 (W2) + 8 (W2@Wg) B-fragments
constexpr int SLAB_B   = 4352;   // per-wave slab: 16 rows x 272 B
constexpr int PAIR_STR = 136;    // pair row stride (bf16): 272 B
constexpr int H_STR    = 72;     // h row stride (bf16): 144 B
constexpr float LOG2E  = 1.4426950408889634f;

static __device__ __forceinline__ ushort_t f2bf(float f) {
    union { float f; unsigned int u; } v; v.f = f;
    const unsigned int r = v.u + 0x7FFFu + ((v.u >> 16) & 1u);   // RNE
    return (ushort_t)(r >> 16);
}

#if __has_builtin(__builtin_amdgcn_exp2f)
static __device__ __forceinline__ float fexp2(float x) { return __builtin_amdgcn_exp2f(x); }
#else
static __device__ __forceinline__ float fexp2(float x) {
    float r; asm("v_exp_f32 %0, %1" : "=v"(r) : "v"(x)); return r;
}
#endif
#if __has_builtin(__builtin_amdgcn_rcpf)
static __device__ __forceinline__ float frcp(float x) { return __builtin_amdgcn_rcpf(x); }
#else
static __device__ __forceinline__ float frcp(float x) {
    float r; asm("v_rcp_f32 %0, %1" : "=v"(r) : "v"(x)); return r;
}
#endif

// ---------------------------------------------------------------------------------
// Cooperative aux kernel: phases 0..3 replace memset + prep + scan + scatter.
// All phases grid-stride; LDS is a tiny 1KB scan buffer.
// ---------------------------------------------------------------------------------

struct AuxParams {
    const float* W1; const float* W2; const float* Wg;
    const float* b2; const float* bg;
    const float* emb; const int* ei;
    ushort_t* wpack; float* bgp; ushort_t* emb_bf;
    int* cnt; int* off; int* bsum; unsigned* sorted; float* summed;
    int N, E, total_emb, cvt_blocks, e4blocks, zblocks, nblocks;
};

__global__ __launch_bounds__(BLOCK, 8)
void fused_aux(AuxParams P) {
    cg::grid_group grid = cg::this_grid();
    __shared__ int s[256];
    const int tid = threadIdx.x;
    const int G   = gridDim.x;

    // ---- phase 0: zero cnt (replaces hipMemsetAsync) ----
    for (int i = blockIdx.x * BLOCK + tid; i < P.N; i += G * BLOCK) P.cnt[i] = 0;
    grid.sync();

    // ---- phase 1: prep branches (weights | emb->bf16 | bgp | histogram | zero summed)
    const int vb1 = 65 + P.cvt_blocks + P.e4blocks + P.zblocks;
    for (int vb = blockIdx.x; vb < vb1; vb += G) {
        if (vb < 64) {                               // weight packing
            const int t = vb * 256 + tid;
            const int f = t >> 9;
            const int l = (t >> 3) & 63;
            const int j = t & 7;
            const int k = ((f < 16) ? (f & 3) : ((f - 16) & 1)) * 32 + (l >> 4) * 8 + j;
            const int n = ((f < 16) ? (f >> 2) : (((f & 7)) >> 1)) * 16 + (l & 15);
            float v;
            if (f < 16)      v = P.W1[k * 64 + n];
            else if (f < 24) v = P.W2[k * 64 + n];
            else {                                   // (W2@Wg)[k][n] * log2(e)
                float sacc = 0.f;
                const float* wr = P.W2 + k * 64;
#pragma unroll 8
                for (int m = 0; m < 64; ++m) sacc += wr[m] * P.Wg[m * 64 + n];
                v = sacc * LOG2E;
            }
            P.wpack[t] = f2bf(v);
        } else if (vb < 64 + P.cvt_blocks) {         // node_emb -> bf16
            const int idx  = (vb - 64) * 256 + tid;
            const int base = idx * 8;
            if (base < P.total_emb) {
                const float4 a = *(const float4*)(P.emb + base);
                const float4 b = *(const float4*)(P.emb + base + 4);
                u16x8 p;
                p[0]=f2bf(a.x); p[1]=f2bf(a.y); p[2]=f2bf(a.z); p[3]=f2bf(a.w);
                p[4]=f2bf(b.x); p[5]=f2bf(b.y); p[6]=f2bf(b.z); p[7]=f2bf(b.w);
                *(u16x8*)(P.emb_bf + base) = p;
            }
        } else if (vb == 64 + P.cvt_blocks) {        // bg' = (b2@Wg + bg) * log2(e)
            const int n = tid;
            if (n < 64) {
                float sacc = P.bg[n];
#pragma unroll 8
                for (int m = 0; m < 64; ++m) sacc += P.b2[m] * P.Wg[m * 64 + n];
                P.bgp[n] = sacc * LOG2E;
            }
        } else if (vb < 65 + P.cvt_blocks + P.e4blocks) {   // edge histogram by src
            const int e = ((vb - 65 - P.cvt_blocks) * 256 + tid) * 4;
            if (e + 3 < P.E) {
                const int4 v = *(const int4*)(P.ei + e);
                atomicAdd(&P.cnt[v.x], 1); atomicAdd(&P.cnt[v.y], 1);
                atomicAdd(&P.cnt[v.z], 1); atomicAdd(&P.cnt[v.w], 1);
            } else {
                for (int k = e; k < P.E; ++k) atomicAdd(&P.cnt[P.ei[k]], 1);
            }
        } else {                                     // zero summed
            const int idx  = (vb - 65 - P.cvt_blocks - P.e4blocks) * 256 + tid;
            const int base = idx * 4;
            if (base < P.total_emb)
                *(float4*)(P.summed + base) = (float4){0.f, 0.f, 0.f, 0.f};
        }
    }
    grid.sync();

    // ---- phase 2: per-256-node exclusive scan -> off, block sums -> bsum ----
    for (int vb = blockIdx.x; vb < P.nblocks; vb += G) {
        const int i = vb * 256 + tid;
        const int x = (i < P.N) ? P.cnt[i] : 0;
        s[tid] = x; __syncthreads();
        for (int d = 1; d < 256; d <<= 1) {
            const int v = (tid >= d) ? s[tid - d] : 0;
            __syncthreads();
            s[tid] += v;
            __syncthreads();
        }
        if (i < P.N) P.off[i] = s[tid] - x;
        if (tid == 255) P.bsum[vb] = s[255];
        __syncthreads();                              // protect s[] for next vb
    }
    grid.sync();

    // ---- phase 3: scatter packed (src<<16|dst); bsum prefix hoisted (once/block) ----
    {
        const int x = (tid < P.nblocks) ? P.bsum[tid] : 0;
        s[tid] = x; __syncthreads();
        for (int d = 1; d < 256; d <<= 1) {
            const int v = (tid >= d) ? s[tid - d] : 0;
            __syncthreads();
            s[tid] += v;
            __syncthreads();
        }
        // s[] now inclusive prefix of bsum; exclusive for block b is s[b-1] (0 if b==0)
        for (int vb = blockIdx.x; vb < P.e4blocks; vb += G) {
            const int e = (vb * 256 + tid) * 4;
            if (e + 3 < P.E) {
                const int4 v = *(const int4*)(P.ei + e);        // src
                const int4 d = *(const int4*)(P.ei + P.E + e);  // dst
                const int bx = v.x >> 8, by = v.y >> 8, bz = v.z >> 8, bw = v.w >> 8;
                P.sorted[(bx ? s[bx - 1] : 0) + atomicAdd(&P.off[v.x], 1)] =
                    ((unsigned)v.x << 16) | (unsigned)d.x;
                P.sorted[(by ? s[by - 1] : 0) + atomicAdd(&P.off[v.y], 1)] =
                    ((unsigned)v.y << 16) | (unsigned)d.y;
                P.sorted[(bz ? s[bz - 1] : 0) + atomicAdd(&P.off[v.z], 1)] =
                    ((unsigned)v.z << 16) | (unsigned)d.z;
                P.sorted[(bw ? s[bw - 1] : 0) + atomicAdd(&P.off[v.w], 1)] =
                    ((unsigned)v.w << 16) | (unsigned)d.w;
            } else {
                for (int k = e; k < P.E; ++k) {
                    const int sv = P.ei[k], b = sv >> 8;
                    P.sorted[(b ? s[b - 1] : 0) + atomicAdd(&P.off[sv], 1)] =
                        ((unsigned)sv << 16) | (unsigned)P.ei[P.E + k];
                }
            }
        }
    }
}

// ---------------- legacy fallback kernels (R10, used only if coop launch fails) ----

__global__ void prep_kernel(const float* __restrict__ W1, const float* __restrict__ W2,
                            const float* __restrict__ Wg,
                            const float* __restrict__ b2, const float* __restrict__ bg,
                            const float* __restrict__ emb, const int* __restrict__ ei,
                            ushort_t* __restrict__ wpack, float* __restrict__ bgp,
                            ushort_t* __restrict__ emb_bf, int* __restrict__ cnt,
                            float* __restrict__ summed,
                            int total_emb, int cvt_blocks, int e4blocks, int E) {
    const int bid = blockIdx.x;
    if (bid < 64) {
        const int t = bid * 256 + threadIdx.x;
        const int f = t >> 9;
        const int l = (t >> 3) & 63;
        const int j = t & 7;
        const int k = ((f < 16) ? (f & 3) : ((f - 16) & 1)) * 32 + (l >> 4) * 8 + j;
        const int n = ((f < 16) ? (f >> 2) : (((f & 7)) >> 1)) * 16 + (l & 15);
        float v;
        if (f < 16)      v = W1[k * 64 + n];
        else if (f < 24) v = W2[k * 64 + n];
        else {
            float s = 0.f;
            const float* wr = W2 + k * 64;
#pragma unroll 8
            for (int m = 0; m < 64; ++m) s += wr[m] * Wg[m * 64 + n];
            v = s * LOG2E;
        }
        wpack[t] = f2bf(v);
    } else if (bid < 64 + cvt_blocks) {
        const int idx  = (bid - 64) * 256 + threadIdx.x;
        const int base = idx * 8;
        if (base < total_emb) {
            const float4 a = *(const float4*)(emb + base);
            const float4 b = *(const float4*)(emb + base + 4);
            u16x8 p;
            p[0]=f2bf(a.x); p[1]=f2bf(a.y); p[2]=f2bf(a.z); p[3]=f2bf(a.w);
            p[4]=f2bf(b.x); p[5]=f2bf(b.y); p[6]=f2bf(b.z); p[7]=f2bf(b.w);
            *(u16x8*)(emb_bf + base) = p;
        }
    } else if (bid == 64 + cvt_blocks) {
        const int n = threadIdx.x;
        if (n < 64) {
            float s = bg[n];
#pragma unroll 8
            for (int m = 0; m < 64; ++m) s += b2[m] * Wg[m * 64 + n];
            bgp[n] = s * LOG2E;
        }
    } else if (bid < 65 + cvt_blocks + e4blocks) {
        const int e = ((bid - 65 - cvt_blocks) * 256 + threadIdx.x) * 4;
        if (e + 3 < E) {
            const int4 v = *(const int4*)(ei + e);
            atomicAdd(&cnt[v.x], 1); atomicAdd(&cnt[v.y], 1);
            atomicAdd(&cnt[v.z], 1); atomicAdd(&cnt[v.w], 1);
        } else {
            for (int k = e; k < E; ++k) atomicAdd(&cnt[ei[k]], 1);
        }
    } else {
        const int idx  = (bid - 65 - cvt_blocks - e4blocks) * 256 + threadIdx.x;
        const int base = idx * 4;
        if (base < total_emb)
            *(float4*)(summed + base) = (float4){0.f, 0.f, 0.f, 0.f};
    }
}

__global__ void scan_block(const int* __restrict__ cnt, int* __restrict__ off,
                           int* __restrict__ bsum, int N) {
    __shared__ int s[256];
    const int t = threadIdx.x, i = blockIdx.x * 256 + t;
    const int x = (i < N) ? cnt[i] : 0;
    s[t] = x; __syncthreads();
    for (int d = 1; d < 256; d <<= 1) {
        const int v = (t >= d) ? s[t - d] : 0;
        __syncthreads();
        s[t] += v;
        __syncthreads();
    }
    if (i < N) off[i] = s[t] - x;
    if (t == 255) bsum[blockIdx.x] = s[255];
}

__global__ void scatter_idx(const int* __restrict__ ei, int* __restrict__ off,
                            const int* __restrict__ bsum, unsigned* __restrict__ sorted,
                            int E, int nb) {
    __shared__ int pref[256];
    const int t = threadIdx.x;
    const int x = (t < nb) ? bsum[t] : 0;
    pref[t] = x; __syncthreads();
    for (int d = 1; d < 256; d <<= 1) {
        const int v = (t >= d) ? pref[t - d] : 0;
        __syncthreads();
        pref[t] += v;
        __syncthreads();
    }
    const int e = (blockIdx.x * blockDim.x + t) * 4;
    if (e + 3 < E) {
        const int4 v = *(const int4*)(ei + e);
        const int4 d = *(const int4*)(ei + E + e);
        const int bx = v.x >> 8, by = v.y >> 8, bz = v.z >> 8, bw = v.w >> 8;
        sorted[(bx ? pref[bx - 1] : 0) + atomicAdd(&off[v.x], 1)] =
            ((unsigned)v.x << 16) | (unsigned)d.x;
        sorted[(by ? pref[by - 1] : 0) + atomicAdd(&off[v.y], 1)] =
            ((unsigned)v.y << 16) | (unsigned)d.y;
        sorted[(bz ? pref[bz - 1] : 0) + atomicAdd(&off[v.z], 1)] =
            ((unsigned)v.z << 16) | (unsigned)d.z;
        sorted[(bw ? pref[bw - 1] : 0) + atomicAdd(&off[v.w], 1)] =
            ((unsigned)v.w << 16) | (unsigned)d.w;
    } else {
        for (int k = e; k < E; ++k) {
            const int s = ei[k], b = s >> 8;
            sorted[(b ? pref[b - 1] : 0) + atomicAdd(&off[s], 1)] =
                ((unsigned)s << 16) | (unsigned)ei[E + k];
        }
    }
}

// ---------------- fused MFMA MLP + register segmented scatter (unchanged R10) ------

__global__ __launch_bounds__(BLOCK, 8)
void edge_mlp_mfma(const ushort_t* __restrict__ emb_bf,   // [N][64] bf16
                   const unsigned* __restrict__ sorted,   // packed (src<<16)|dst, sorted
                   const ushort_t* __restrict__ wpack,    // 32 packed B-frags
                   const float* __restrict__ b1, const float* __restrict__ b2,
                   const float* __restrict__ bgp,         // (b2@Wg + bg) * log2e
                   const int*   __restrict__ cnt,         // per-node edge counts
                   float* __restrict__ summed,            // [N][D] pre-zeroed
                   int E)
{
    __shared__ char  slab[4][SLAB_B];    // 17408 B: per-wave pair then h
    __shared__ int   srcIds[TILE];
    __shared__ float rcS[TILE];

    const int tid = threadIdx.x;

    // ---- stage: one packed 4B load -> two 128B row gathers into per-wave slab ----
    {
        const int e = tid >> 2, q4 = tid & 3;
        ushort_t* prow = (ushort_t*)&slab[e >> 4][(e & 15) * (PAIR_STR * 2)];
        const int ide = blockIdx.x * TILE + e;
        if (ide < E) {
            const unsigned p = sorted[ide];
            const int s  = (int)(p >> 16);
            const int dn = (int)(p & 0xFFFFu);
            if (q4 == 0) { srcIds[e] = s; rcS[e] = frcp(fmaxf((float)cnt[s], 1.0f)); }
            const ushort_t* sr = emb_bf + (size_t)s  * D + q4 * 16;
            const ushort_t* dr = emb_bf + (size_t)dn * D + q4 * 16;
            *(u16x8*)&prow[q4 * 16]          = *(const u16x8*)sr;
            *(u16x8*)&prow[q4 * 16 + 8]      = *(const u16x8*)(sr + 8);
            *(u16x8*)&prow[64 + q4 * 16]     = *(const u16x8*)dr;
            *(u16x8*)&prow[64 + q4 * 16 + 8] = *(const u16x8*)(dr + 8);
        } else {
            if (q4 == 0) { srcIds[e] = -1; rcS[e] = 1.0f; }
            const u16x8 z = {0,0,0,0,0,0,0,0};
            *(u16x8*)&prow[q4 * 16]          = z;
            *(u16x8*)&prow[q4 * 16 + 8]      = z;
            *(u16x8*)&prow[64 + q4 * 16]     = z;
            *(u16x8*)&prow[64 + q4 * 16 + 8] = z;
        }
    }

    const int w    = tid >> 6;
    const int ln   = tid & 63;
    const int quad = ln >> 4;
    const int cn   = ln & 15;
    ushort_t* pairW = (ushort_t*)slab[w];   // [16][136]
    ushort_t* hW    = (ushort_t*)slab[w];   // [16][72]

    // ---- GEMM1: h = relu(pair @ W1 + b1), M=16 K=128 N=64 (kc-outer) ----
    f32x4 acc1[4];
#pragma unroll
    for (int nt = 0; nt < 4; ++nt) {
        const float b = b1[nt * 16 + cn];
        acc1[nt] = (f32x4){b, b, b, b};
    }
#pragma unroll
    for (int kc = 0; kc < 4; ++kc) {
        const bf16x8 a = *(const bf16x8*)&pairW[cn * PAIR_STR + kc * 32 + quad * 8];
#pragma unroll
        for (int nt = 0; nt < 4; ++nt) {
            const bf16x8 bf = *(const bf16x8*)(wpack + ((nt * 4 + kc) * 64 + ln) * 8);
            acc1[nt] = __builtin_amdgcn_mfma_f32_16x16x32_bf16(a, bf, acc1[nt], 0, 0, 0);
        }
    }
#pragma unroll
    for (int nt = 0; nt < 4; ++nt)
#pragma unroll
        for (int r = 0; r < 4; ++r)
            hW[(quad * 4 + r) * H_STR + nt * 16 + cn] = f2bf(fmaxf(acc1[nt][r], 0.f));

    // ---- GEMM2+3 fused (kc-outer) ----
    f32x4 acc2[4], accg[4];
#pragma unroll
    for (int nt = 0; nt < 4; ++nt) {
        const float b  = b2 [nt * 16 + cn];
        const float bG = bgp[nt * 16 + cn];
        acc2[nt] = (f32x4){b, b, b, b};
        accg[nt] = (f32x4){bG, bG, bG, bG};
    }
#pragma unroll
    for (int kc = 0; kc < 2; ++kc) {
        const bf16x8 a = *(const bf16x8*)&hW[cn * H_STR + kc * 32 + quad * 8];
#pragma unroll
        for (int nt = 0; nt < 4; ++nt) {
            const bf16x8 bf2 = *(const bf16x8*)(wpack + ((16 + nt * 2 + kc) * 64 + ln) * 8);
            const bf16x8 bfg = *(const bf16x8*)(wpack + ((24 + nt * 2 + kc) * 64 + ln) * 8);
            acc2[nt] = __builtin_amdgcn_mfma_f32_16x16x32_bf16(a, bf2, acc2[nt], 0, 0, 0);
            accg[nt] = __builtin_amdgcn_mfma_f32_16x16x32_bf16(a, bfg, accg[nt], 0, 0, 0);
        }
    }

    // ---- gated = interaction * sigmoid(gate_pre), folded into per-lane PREFIX sums ----
    float P[4][4];
#pragma unroll
    for (int nt = 0; nt < 4; ++nt) {
#pragma unroll
        for (int r = 0; r < 4; ++r) {
            const float ex = fexp2(-accg[nt][r]);
            P[nt][r] = acc2[nt][r] * frcp(1.0f + ex);
        }
        P[nt][1] += P[nt][0];
        P[nt][2] += P[nt][1];
        P[nt][3] += P[nt][2];
    }

    // ---- segmented scatter: ballot boundary mask + scalar segment loop ----
    {
        const int   rbase  = 16 * w;
        const int   myRow  = ln & 15;
        const int   mySrc  = srcIds[rbase + myRow];
        const float myRc   = rcS[rbase + myRow];
        const int   prevSrc = srcIds[rbase + ((myRow + 15) & 15)];
        unsigned bmask = ((unsigned)__ballot(mySrc != prevSrc) & 0xFFFFu) | 1u;
        const int q4r = 4 * quad;
        while (bmask) {
            const int a = __builtin_ctz(bmask);
            bmask &= (bmask - 1u);
            const int b = bmask ? __builtin_ctz(bmask) : 16;
            const int sseg = __builtin_amdgcn_readlane(mySrc, a);
            if (sseg >= 0) {
                const int lo  = a - q4r, hi = b - q4r;
                const int clo = lo < 0 ? 0 : (lo > 4 ? 4 : lo);
                const int chi = hi < 0 ? 0 : (hi > 4 ? 4 : hi);
                const bool ge1 = chi > 1, ge2 = chi > 2, ge3 = chi > 3;
                const bool l0 = clo > 0, l1 = clo > 1, l2 = clo > 2;
                const bool valid = chi > clo;
                float t[4];
#pragma unroll
                for (int nt = 0; nt < 4; ++nt) {
                    const float sh = ge2 ? (ge3 ? P[nt][3] : P[nt][2])
                                         : (ge1 ? P[nt][1] : P[nt][0]);
                    const float sl = l1 ? (l2 ? P[nt][2] : P[nt][1])
                                        : (l0 ? P[nt][0] : 0.f);
                    t[nt] = valid ? sh - sl : 0.f;
                }
                t[0] += __shfl_xor(t[0], 16); t[0] += __shfl_xor(t[0], 32);
                t[1] += __shfl_xor(t[1], 16); t[1] += __shfl_xor(t[1], 32);
                t[2] += __shfl_xor(t[2], 16); t[2] += __shfl_xor(t[2], 32);
                t[3] += __shfl_xor(t[3], 16); t[3] += __shfl_xor(t[3], 32);
                const float tot = (quad < 2) ? (quad == 0 ? t[0] : t[1])
                                             : (quad == 2 ? t[2] : t[3]);
                const float rc = __uint_as_float(
                    __builtin_amdgcn_readlane(__float_as_uint(myRc), a));
                unsafeAtomicAdd(&summed[(size_t)sseg * D + ln], tot * rc);
            }
        }
    }
}

extern "C" void kernel_launch(void* const* d_in, const int* in_sizes, int n_in,
                              void* d_out, int out_size, void* d_ws, size_t ws_size,
                              hipStream_t stream) {
    const float* node_emb   = (const float*)d_in[0];
    const int*   edge_index = (const int*)d_in[1];
    const float* W1 = (const float*)d_in[2];
    const float* b1 = (const float*)d_in[3];
    const float* W2 = (const float*)d_in[4];
    const float* b2 = (const float*)d_in[5];
    const float* Wg = (const float*)d_in[6];
    const float* bg = (const float*)d_in[7];

    const int N = in_sizes[0] / D;
    const int E = in_sizes[1] / 2;
    const int total_emb = N * D;

    // ws layout == R5..R10's proven extent:
    // cnt[N] | off[N] | bsum[256] | sorted[E u32] | bgp[64 f32] | wpack[16K bf16] | emb_bf
    int* cnt    = (int*)d_ws;
    int* off    = cnt + N;
    int* bsum   = off + N;
    unsigned* sorted = (unsigned*)(bsum + 256);
    float* bgp  = (float*)(sorted + E);
    ushort_t* wpack  = (ushort_t*)(bgp + 64);
    ushort_t* emb_bf = wpack + NFRAG * 512;

    float* summed = (float*)d_out;

    const int cvt_blocks = (total_emb / 8 + 255) / 256;
    const int e4blocks   = ((E + 3) / 4 + 255) / 256;
    const int zblocks    = (total_emb / 4 + 255) / 256;
    const int nblocks    = (N + 255) / 256;   // 196 (must be <= 256 for inline prefix)

    // ---- cooperative grid size (static-cached occupancy query) ----
    static int g_grid = -1;
    if (g_grid < 0) {
        int perCU = 0;
        hipError_t oe = hipOccupancyMaxActiveBlocksPerMultiprocessor(
            &perCU, reinterpret_cast<const void*>(&fused_aux), BLOCK, 0);
        int nCU = 256;
        hipDeviceProp_t prop;
        int dev = 0;
        if (hipGetDevice(&dev) == hipSuccess &&
            hipGetDeviceProperties(&prop, dev) == hipSuccess)
            nCU = prop.multiProcessorCount;
        g_grid = (oe == hipSuccess && perCU > 0) ? perCU * nCU : 0;
        if (g_grid > 4096) g_grid = 4096;
    }

    bool coop_ok = false;
    if (g_grid > 0) {
        AuxParams P;
        P.W1 = W1; P.W2 = W2; P.Wg = Wg; P.b2 = b2; P.bg = bg;
        P.emb = node_emb; P.ei = edge_index;
        P.wpack = wpack; P.bgp = bgp; P.emb_bf = emb_bf;
        P.cnt = cnt; P.off = off; P.bsum = bsum; P.sorted = sorted; P.summed = summed;
        P.N = N; P.E = E; P.total_emb = total_emb;
        P.cvt_blocks = cvt_blocks; P.e4blocks = e4blocks; P.zblocks = zblocks;
        P.nblocks = nblocks;
        void* kargs[] = { (void*)&P };
        coop_ok = hipLaunchCooperativeKernel(reinterpret_cast<const void*>(&fused_aux),
                                             dim3(g_grid), dim3(BLOCK), kargs, 0,
                                             stream) == hipSuccess;
    }

    if (!coop_ok) {    // legacy 5-dispatch path (R10, proven)
        hipMemsetAsync(cnt, 0, sizeof(int) * (size_t)N, stream);
        prep_kernel<<<64 + cvt_blocks + 1 + e4blocks + zblocks, 256, 0, stream>>>(
            W1, W2, Wg, b2, bg, node_emb, edge_index,
            wpack, bgp, emb_bf, cnt, summed, total_emb, cvt_blocks, e4blocks, E);
        scan_block <<<nblocks, 256, 0, stream>>>(cnt, off, bsum, N);
        scatter_idx<<<e4blocks, 256, 0, stream>>>(edge_index, off, bsum, sorted, E, nblocks);
    }

    const int ntiles = (E + TILE - 1) / TILE;
    edge_mlp_mfma<<<ntiles, BLOCK, 0, stream>>>(emb_bf, sorted, wpack,
                                                b1, b2, bgp, cnt, summed, E);
}

// Round 3
// 453.505 us; speedup vs baseline: 1.2786x; 1.2786x over previous
//
#include <hip/hip_runtime.h>

// SocialPoolingLayer: fused edge-MLP (relu(pair@W1+b1)@W2+b2, sigmoid gate, elemwise
// product) + scatter-mean by src node.
// Round 12: R11's cooperative aux REVERTED (grid.sync spun 746us, L2 flush 97MB WRITE
// -- cross-XCD sync anti-pattern). Aux = proven R10 5-dispatch chain, byte-identical.
// Main kernel rebuilt as PERSISTENT + PIPELINED (T14/T3 in plain HIP):
//  - grid 1280 (5 blocks/CU, LDS-limited), contiguous tile chunks per block
//  - global_load_lds direct staging into chunk-major swizzled LDS:
//      off(r,c) = (c>>2)*1024 + (c&3)*256 + r*16
//    => staging dest is EXACTLY linear lane*16 (m104 constraint) AND the MFMA A-frag
//    read is EXACTLY kc*1024 + ln*16 (conflict-free ds_read_b128 both sides).
//  - per-wave double-buffered slabs, barrier-free; counted s_waitcnt vmcnt(6)
//    (prefetch t+1 = 4 gathers + cnt + sorted = exactly 6 VMEM ops in flight)
//  - srcIds/rcS LDS arrays gone: packed ids live in registers, prevSrc via __shfl,
//    rc via readlane at flush.

typedef unsigned short ushort_t;
typedef __attribute__((ext_vector_type(8))) short     bf16x8;   // 8 bf16 = 4 VGPRs
typedef __attribute__((ext_vector_type(8))) unsigned short u16x8;
typedef __attribute__((ext_vector_type(4))) float     f32x4;

constexpr int D        = 64;
constexpr int TILE     = 64;     // edges per block-tile (4 waves x 16 edges)
constexpr int BLOCK    = 256;
constexpr int NFRAG    = 32;     // 16 (W1) + 8 (W2) + 8 (W2@Wg) B-fragments
constexpr int GRID_MLP = 1280;   // 5 blocks/CU x 256 CU (LDS 32KB/block)
constexpr float LOG2E  = 1.4426950408889634f;

static __device__ __forceinline__ ushort_t f2bf(float f) {
    union { float f; unsigned int u; } v; v.f = f;
    const unsigned int r = v.u + 0x7FFFu + ((v.u >> 16) & 1u);   // RNE
    return (ushort_t)(r >> 16);
}

static __device__ __forceinline__ float fexp2(float x) {
    float r; asm("v_exp_f32 %0, %1" : "=v"(r) : "v"(x)); return r;
}
static __device__ __forceinline__ float frcp(float x) {
    float r; asm("v_rcp_f32 %0, %1" : "=v"(r) : "v"(x)); return r;
}

// global -> LDS direct (16B/lane). LDS dest: wave-uniform base + lane*16 (m104).
static __device__ __forceinline__ void gload16(const void* g, void* l) {
    __builtin_amdgcn_global_load_lds(
        (const __attribute__((address_space(1))) void*)g,
        (__attribute__((address_space(3))) void*)l, 16, 0, 0);
}

// Stage one wave-tile (16 edges x 256B pair rows) into chunk-major swizzled slab.
// Lane l: edge row r = l&15, chunk-quarter cq = l>>4.
// instr i covers chunk c = cq + 4i; c<8 = src half, c>=8 = dst half.
static __device__ __forceinline__ void stage_tile(const ushort_t* __restrict__ emb_bf,
                                                  char* lbuf, unsigned pk, bool valid,
                                                  int cq) {
    const unsigned s = valid ? (pk >> 16)     : 0u;
    const unsigned d = valid ? (pk & 0xFFFFu) : 0u;
    const ushort_t* sp = emb_bf + (size_t)s * D + cq * 8;
    const ushort_t* dp = emb_bf + (size_t)d * D + cq * 8;
    gload16(sp,      lbuf);
    gload16(sp + 32, lbuf + 1024);
    gload16(dp,      lbuf + 2048);
    gload16(dp + 32, lbuf + 3072);
}

// ---- prep: pack + W2Wg + bg' + emb->bf16 + histogram + summed-zero, one dispatch ----
// Weight fragment layout (verified R3): frag f, lane l, elem j -> W[k][n],
// k = kc*32 + (l>>4)*8 + j, n = nt*16 + (l&15).
// f in [0,16): W1; [16,24): W2; [24,32): (W2@Wg)*log2e.

__global__ void prep_kernel(const float* __restrict__ W1, const float* __restrict__ W2,
                            const float* __restrict__ Wg,
                            const float* __restrict__ b2, const float* __restrict__ bg,
                            const float* __restrict__ emb, const int* __restrict__ ei,
                            ushort_t* __restrict__ wpack, float* __restrict__ bgp,
                            ushort_t* __restrict__ emb_bf, int* __restrict__ cnt,
                            float* __restrict__ summed,
                            int total_emb, int cvt_blocks, int e4blocks, int E) {
    const int bid = blockIdx.x;
    if (bid < 64) {                              // 64*256 == NFRAG*512: weight packing
        const int t = bid * 256 + threadIdx.x;
        const int f = t >> 9;
        const int l = (t >> 3) & 63;
        const int j = t & 7;
        const int k = ((f < 16) ? (f & 3) : ((f - 16) & 1)) * 32 + (l >> 4) * 8 + j;
        const int n = ((f < 16) ? (f >> 2) : (((f & 7)) >> 1)) * 16 + (l & 15);
        float v;
        if (f < 16)      v = W1[k * 64 + n];
        else if (f < 24) v = W2[k * 64 + n];
        else {                                   // (W2@Wg)[k][n] * log2(e)
            float s = 0.f;
            const float* wr = W2 + k * 64;
#pragma unroll 8
            for (int m = 0; m < 64; ++m) s += wr[m] * Wg[m * 64 + n];
            v = s * LOG2E;
        }
        wpack[t] = f2bf(v);
    } else if (bid < 64 + cvt_blocks) {          // node_emb -> bf16
        const int idx  = (bid - 64) * 256 + threadIdx.x;
        const int base = idx * 8;
        if (base < total_emb) {
            const float4 a = *(const float4*)(emb + base);
            const float4 b = *(const float4*)(emb + base + 4);
            u16x8 p;
            p[0]=f2bf(a.x); p[1]=f2bf(a.y); p[2]=f2bf(a.z); p[3]=f2bf(a.w);
            p[4]=f2bf(b.x); p[5]=f2bf(b.y); p[6]=f2bf(b.z); p[7]=f2bf(b.w);
            *(u16x8*)(emb_bf + base) = p;
        }
    } else if (bid == 64 + cvt_blocks) {         // bg' = (b2@Wg + bg) * log2(e)
        const int n = threadIdx.x;
        if (n < 64) {
            float s = bg[n];
#pragma unroll 8
            for (int m = 0; m < 64; ++m) s += b2[m] * Wg[m * 64 + n];
            bgp[n] = s * LOG2E;
        }
    } else if (bid < 65 + cvt_blocks + e4blocks) {   // edge histogram by src
        const int e = ((bid - 65 - cvt_blocks) * 256 + threadIdx.x) * 4;
        if (e + 3 < E) {
            const int4 v = *(const int4*)(ei + e);
            atomicAdd(&cnt[v.x], 1); atomicAdd(&cnt[v.y], 1);
            atomicAdd(&cnt[v.z], 1); atomicAdd(&cnt[v.w], 1);
        } else {
            for (int k = e; k < E; ++k) atomicAdd(&cnt[ei[k]], 1);
        }
    } else {                                     // zero summed
        const int idx  = (bid - 65 - cvt_blocks - e4blocks) * 256 + threadIdx.x;
        const int base = idx * 4;
        if (base < total_emb)
            *(float4*)(summed + base) = (float4){0.f, 0.f, 0.f, 0.f};
    }
}

// ---------------- scan: per-block exclusive offsets + block sums ----------

__global__ void scan_block(const int* __restrict__ cnt, int* __restrict__ off,
                           int* __restrict__ bsum, int N) {
    __shared__ int s[256];
    const int t = threadIdx.x, i = blockIdx.x * 256 + t;
    const int x = (i < N) ? cnt[i] : 0;
    s[t] = x; __syncthreads();
    for (int d = 1; d < 256; d <<= 1) {
        const int v = (t >= d) ? s[t - d] : 0;
        __syncthreads();
        s[t] += v;
        __syncthreads();
    }
    if (i < N) off[i] = s[t] - x;                 // block-local exclusive prefix
    if (t == 255) bsum[blockIdx.x] = s[255];
}

// scatter with inline bsum prefix (nb <= 256); off[] doubles as insertion cursor.
// Writes packed (src<<16)|dst per slot -- requires N < 65536.
__global__ void scatter_idx(const int* __restrict__ ei, int* __restrict__ off,
                            const int* __restrict__ bsum, unsigned* __restrict__ sorted,
                            int E, int nb) {
    __shared__ int pref[256];
    const int t = threadIdx.x;
    const int x = (t < nb) ? bsum[t] : 0;
    pref[t] = x; __syncthreads();
    for (int d = 1; d < 256; d <<= 1) {
        const int v = (t >= d) ? pref[t - d] : 0;
        __syncthreads();
        pref[t] += v;
        __syncthreads();
    }
    const int e = (blockIdx.x * blockDim.x + t) * 4;
    if (e + 3 < E) {
        const int4 v = *(const int4*)(ei + e);        // src
        const int4 d = *(const int4*)(ei + E + e);    // dst
        const int bx = v.x >> 8, by = v.y >> 8, bz = v.z >> 8, bw = v.w >> 8;
        sorted[(bx ? pref[bx - 1] : 0) + atomicAdd(&off[v.x], 1)] =
            ((unsigned)v.x << 16) | (unsigned)d.x;
        sorted[(by ? pref[by - 1] : 0) + atomicAdd(&off[v.y], 1)] =
            ((unsigned)v.y << 16) | (unsigned)d.y;
        sorted[(bz ? pref[bz - 1] : 0) + atomicAdd(&off[v.z], 1)] =
            ((unsigned)v.z << 16) | (unsigned)d.z;
        sorted[(bw ? pref[bw - 1] : 0) + atomicAdd(&off[v.w], 1)] =
            ((unsigned)v.w << 16) | (unsigned)d.w;
    } else {
        for (int k = e; k < E; ++k) {
            const int s = ei[k], b = s >> 8;
            sorted[(b ? pref[b - 1] : 0) + atomicAdd(&off[s], 1)] =
                ((unsigned)s << 16) | (unsigned)ei[E + k];
        }
    }
}

// ------------- persistent pipelined MFMA MLP + register segmented scatter ----------
// Per-wave double-buffered slab (2 x 4096B), barrier-free (all LDS wave-private).
// Chunk-major swizzle: off(r,c) = (c>>2)*1024 + (c&3)*256 + r*16
//   staging instr i, lane l -> (r=l&15, c=(l>>4)+4i) lands at i*1024 + l*16 (linear!)
//   A-frag read (row cn, chunk kc*4+quad) = kc*1024 + ln*16 (conflict-free b128)

__global__ __launch_bounds__(BLOCK, 5)
void edge_mlp_mfma(const ushort_t* __restrict__ emb_bf,   // [N][64] bf16
                   const unsigned* __restrict__ sorted,   // packed (src<<16)|dst, sorted
                   const ushort_t* __restrict__ wpack,    // 32 packed B-frags
                   const float* __restrict__ b1, const float* __restrict__ b2,
                   const float* __restrict__ bgp,         // (b2@Wg + bg) * log2e
                   const int*   __restrict__ cnt,         // per-node edge counts
                   float* __restrict__ summed,            // [N][D] pre-zeroed
                   int E, int ntiles, int nblk)
{
    __shared__ __align__(16) char lds[4][2][4096];   // 32 KB: per-wave dbuf slabs

    const int tid  = threadIdx.x;
    const int w    = tid >> 6;
    const int ln   = tid & 63;
    const int quad = ln >> 4;
    const int cn   = ln & 15;
    const int row  = ln & 15;

    const int start = (int)(((long long)blockIdx.x * ntiles) / nblk);
    const int end   = (int)(((long long)(blockIdx.x + 1) * ntiles) / nblk);
    if (start >= end) return;

    // hoisted biases (loop-invariant)
    float bb1[4], bb2[4], bbg[4];
#pragma unroll
    for (int nt = 0; nt < 4; ++nt) {
        bb1[nt] = b1 [nt * 16 + cn];
        bb2[nt] = b2 [nt * 16 + cn];
        bbg[nt] = bgp[nt * 16 + cn];
    }

    const int ebase = w * 16 + row;          // lane's edge slot within a tile

    // ---- prologue: ids for tile `start`, stage it, ids for start+1 ----
    unsigned pk_cur, pk_next;
    bool     v_cur,  v_next;
    int      cv_cur, cv_next = 0;
    {
        const int ide = start * TILE + ebase;
        v_cur  = ide < E;
        pk_cur = sorted[v_cur ? ide : (E - 1)];
        stage_tile(emb_bf, lds[w][0], pk_cur, v_cur, quad);
        cv_cur = cnt[v_cur ? (int)(pk_cur >> 16) : 0];
        const int ide2 = (start + 1) * TILE + ebase;
        v_next  = ide2 < E;
        pk_next = sorted[v_next ? ide2 : (E - 1)];
    }

    int par = 0;
    for (int t = start; t < end; ++t) {
        char* cbuf = lds[w][par];

        unsigned pk3 = 0; bool v3 = false;
        if (t + 1 < end) {
            // prefetch tile t+1: exactly 6 VMEM ops (4 gathers + cnt + sorted)
            stage_tile(emb_bf, lds[w][par ^ 1], pk_next, v_next, quad);
            cv_next = cnt[v_next ? (int)(pk_next >> 16) : 0];
            const int ide3 = (t + 2) * TILE + ebase;
            v3  = ide3 < E;
            pk3 = sorted[v3 ? ide3 : (E - 1)];
            asm volatile("s_waitcnt vmcnt(6)" ::: "memory");  // tile t's data landed
        } else {
            asm volatile("s_waitcnt vmcnt(0)" ::: "memory");
        }

        // ---- GEMM1: h = relu(pair @ W1 + b1), M=16 K=128 N=64 (kc-outer) ----
        f32x4 acc1[4];
#pragma unroll
        for (int nt = 0; nt < 4; ++nt)
            acc1[nt] = (f32x4){bb1[nt], bb1[nt], bb1[nt], bb1[nt]};
#pragma unroll
        for (int kc = 0; kc < 4; ++kc) {
            const bf16x8 a = *(const bf16x8*)(cbuf + kc * 1024 + ln * 16);
#pragma unroll
            for (int nt = 0; nt < 4; ++nt) {
                const bf16x8 bf = *(const bf16x8*)(wpack + ((nt * 4 + kc) * 64 + ln) * 8);
                acc1[nt] = __builtin_amdgcn_mfma_f32_16x16x32_bf16(a, bf, acc1[nt], 0, 0, 0);
            }
        }
        // h tile into same swizzle (chunks 0..7 -> bytes [0,2048) of cbuf)
#pragma unroll
        for (int nt = 0; nt < 4; ++nt) {
            const int c = nt * 2 + (cn >> 3);
            char* hb = cbuf + (c >> 2) * 1024 + (c & 3) * 256 + quad * 64 + (cn & 7) * 2;
#pragma unroll
            for (int rr = 0; rr < 4; ++rr)
                *(ushort_t*)(hb + rr * 16) = f2bf(fmaxf(acc1[nt][rr], 0.f));
        }

        // ---- GEMM2+3 fused: interaction = h@W2+b2 ; gate_pre = h@(W2Wg*log2e)+bg' ----
        f32x4 acc2[4], accg[4];
#pragma unroll
        for (int nt = 0; nt < 4; ++nt) {
            acc2[nt] = (f32x4){bb2[nt], bb2[nt], bb2[nt], bb2[nt]};
            accg[nt] = (f32x4){bbg[nt], bbg[nt], bbg[nt], bbg[nt]};
        }
#pragma unroll
        for (int kc = 0; kc < 2; ++kc) {
            const bf16x8 a = *(const bf16x8*)(cbuf + kc * 1024 + ln * 16);
#pragma unroll
            for (int nt = 0; nt < 4; ++nt) {
                const bf16x8 bf2 = *(const bf16x8*)(wpack + ((16 + nt * 2 + kc) * 64 + ln) * 8);
                const bf16x8 bfg = *(const bf16x8*)(wpack + ((24 + nt * 2 + kc) * 64 + ln) * 8);
                acc2[nt] = __builtin_amdgcn_mfma_f32_16x16x32_bf16(a, bf2, acc2[nt], 0, 0, 0);
                accg[nt] = __builtin_amdgcn_mfma_f32_16x16x32_bf16(a, bfg, accg[nt], 0, 0, 0);
            }
        }

        // ---- gated = interaction * sigmoid(gate_pre) -> per-lane PREFIX sums ----
        float P[4][4];
#pragma unroll
        for (int nt = 0; nt < 4; ++nt) {
#pragma unroll
            for (int r = 0; r < 4; ++r) {
                const float ex = fexp2(-accg[nt][r]);
                P[nt][r] = acc2[nt][r] * frcp(1.0f + ex);
            }
            P[nt][1] += P[nt][0];
            P[nt][2] += P[nt][1];
            P[nt][3] += P[nt][2];
        }

        // ---- segmented scatter: ballot boundary mask + scalar segment loop ----
        {
            const int   mySrc = v_cur ? (int)(pk_cur >> 16) : -1;
            const float myRc  = frcp(fmaxf((float)cv_cur, 1.0f));
            const int   prevLane = (ln & 48) | ((ln + 15) & 15);
            const int   prevSrc  = __shfl(mySrc, prevLane);
            unsigned bmask = ((unsigned)__ballot(mySrc != prevSrc) & 0xFFFFu) | 1u;
            const int q4r = 4 * quad;
            while (bmask) {
                const int a = __builtin_ctz(bmask);
                bmask &= (bmask - 1u);
                const int b = bmask ? __builtin_ctz(bmask) : 16;
                const int sseg = __builtin_amdgcn_readlane(mySrc, a);
                if (sseg >= 0) {
                    const int lo  = a - q4r, hi = b - q4r;
                    const int clo = lo < 0 ? 0 : (lo > 4 ? 4 : lo);
                    const int chi = hi < 0 ? 0 : (hi > 4 ? 4 : hi);
                    const bool ge1 = chi > 1, ge2 = chi > 2, ge3 = chi > 3;
                    const bool l0 = clo > 0, l1 = clo > 1, l2 = clo > 2;
                    const bool valid = chi > clo;
                    float tt[4];
#pragma unroll
                    for (int nt = 0; nt < 4; ++nt) {
                        const float sh = ge2 ? (ge3 ? P[nt][3] : P[nt][2])
                                             : (ge1 ? P[nt][1] : P[nt][0]);
                        const float sl = l1 ? (l2 ? P[nt][2] : P[nt][1])
                                            : (l0 ? P[nt][0] : 0.f);
                        tt[nt] = valid ? sh - sl : 0.f;
                    }
                    tt[0] += __shfl_xor(tt[0], 16); tt[0] += __shfl_xor(tt[0], 32);
                    tt[1] += __shfl_xor(tt[1], 16); tt[1] += __shfl_xor(tt[1], 32);
                    tt[2] += __shfl_xor(tt[2], 16); tt[2] += __shfl_xor(tt[2], 32);
                    tt[3] += __shfl_xor(tt[3], 16); tt[3] += __shfl_xor(tt[3], 32);
                    const float tot = (quad < 2) ? (quad == 0 ? tt[0] : tt[1])
                                                 : (quad == 2 ? tt[2] : tt[3]);
                    const float rc = __uint_as_float(
                        __builtin_amdgcn_readlane(__float_as_uint(myRc), a));
                    unsafeAtomicAdd(&summed[(size_t)sseg * D + ln], tot * rc);
                }
            }
        }

        // rotate pipeline registers
        pk_cur = pk_next; v_cur = v_next; cv_cur = cv_next;
        pk_next = pk3;    v_next = v3;
        par ^= 1;
    }
}

extern "C" void kernel_launch(void* const* d_in, const int* in_sizes, int n_in,
                              void* d_out, int out_size, void* d_ws, size_t ws_size,
                              hipStream_t stream) {
    const float* node_emb   = (const float*)d_in[0];
    const int*   edge_index = (const int*)d_in[1];
    const float* W1 = (const float*)d_in[2];
    const float* b1 = (const float*)d_in[3];
    const float* W2 = (const float*)d_in[4];
    const float* b2 = (const float*)d_in[5];
    const float* Wg = (const float*)d_in[6];
    const float* bg = (const float*)d_in[7];

    const int N = in_sizes[0] / D;
    const int E = in_sizes[1] / 2;
    const int total_emb = N * D;

    // ws layout == R5..R10's proven extent:
    // cnt[N] | off[N] | bsum[256] | sorted[E u32] | bgp[64 f32] | wpack[16K bf16] | emb_bf
    int* cnt    = (int*)d_ws;
    int* off    = cnt + N;
    int* bsum   = off + N;
    unsigned* sorted = (unsigned*)(bsum + 256);
    float* bgp  = (float*)(sorted + E);
    ushort_t* wpack  = (ushort_t*)(bgp + 64);
    ushort_t* emb_bf = wpack + NFRAG * 512;

    float* summed = (float*)d_out;

    hipMemsetAsync(cnt, 0, sizeof(int) * (size_t)N, stream);   // must precede prep's hist

    const int cvt_blocks = (total_emb / 8 + 255) / 256;
    const int e4blocks   = ((E + 3) / 4 + 255) / 256;
    const int zblocks    = (total_emb / 4 + 255) / 256;
    prep_kernel<<<64 + cvt_blocks + 1 + e4blocks + zblocks, 256, 0, stream>>>(
        W1, W2, Wg, b2, bg, node_emb, edge_index,
        wpack, bgp, emb_bf, cnt, summed, total_emb, cvt_blocks, e4blocks, E);

    const int nblocks = (N + 255) / 256;   // 196 (must be <= 256 for inline prefix)
    scan_block <<<nblocks, 256, 0, stream>>>(cnt, off, bsum, N);
    scatter_idx<<<e4blocks, 256, 0, stream>>>(edge_index, off, bsum, sorted, E, nblocks);

    const int ntiles = (E + TILE - 1) / TILE;
    const int nblk   = (ntiles < GRID_MLP) ? ntiles : GRID_MLP;
    edge_mlp_mfma<<<nblk, BLOCK, 0, stream>>>(emb_bf, sorted, wpack,
                                              b1, b2, bgp, cnt, summed,
                                              E, ntiles, nblk);
}

// Round 4
// 297.180 us; speedup vs baseline: 1.9512x; 1.5260x over previous
//
#include <hip/hip_runtime.h>

// SocialPoolingLayer: fused edge-MLP (relu(pair@W1+b1)@W2+b2, sigmoid gate, elemwise
// product) + scatter-mean by src node.
// Round 13: SORT PIPELINE DELETED. R3 showed the aux chain (memset+prep+scan+scatter)
// is a ~150us constant while edge_mlp is 78us. The sort existed only to amortize the
// flush atomics; instead the flush now emits PER-EDGE direct atomics (row r of the
// C-fragment lives in quad r>>2's 16 lanes -> 4 rounds x 4 unsafeAtomicAdd per lane,
// no shuffles/prefix/segments), and the mean divide moves to a tiny finalize pass
// (sum-then-divide == reference rounding). cnt histogram folds into main (1 atomic/
// edge, overlapped with MFMA); cnt zeroing folds into prep. 5 dispatches -> 3.
// Main staging/GEMM structure is R1's proven form (4-consecutive-lanes-per-row
// coalescing, wave-private slabs, barrier-free). R3's global_load_lds gather + 
// persistent-chunk experiment REVERTED (FETCH 30->429MB: adjacent lanes must stay on
// the same row for 64B segment coalescing; dispatch-order tiling gives L2 locality).

typedef unsigned short ushort_t;
typedef __attribute__((ext_vector_type(8))) short     bf16x8;   // 8 bf16 = 4 VGPRs
typedef __attribute__((ext_vector_type(8))) unsigned short u16x8;
typedef __attribute__((ext_vector_type(4))) float     f32x4;

constexpr int D        = 64;
constexpr int TILE     = 64;     // edges per block (4 waves x 16 edges)
constexpr int BLOCK    = 256;
constexpr int NFRAG    = 32;     // 16 (W1) + 8 (W2) + 8 (W2@Wg) B-fragments
constexpr int SLAB_B   = 4352;   // per-wave slab: 16 rows x 272 B
constexpr int PAIR_STR = 136;    // pair row stride (bf16): 272 B
constexpr int H_STR    = 72;     // h row stride (bf16): 144 B
constexpr float LOG2E  = 1.4426950408889634f;

static __device__ __forceinline__ ushort_t f2bf(float f) {
    union { float f; unsigned int u; } v; v.f = f;
    const unsigned int r = v.u + 0x7FFFu + ((v.u >> 16) & 1u);   // RNE
    return (ushort_t)(r >> 16);
}

static __device__ __forceinline__ float fexp2(float x) {
    float r; asm("v_exp_f32 %0, %1" : "=v"(r) : "v"(x)); return r;
}
static __device__ __forceinline__ float frcp(float x) {
    float r; asm("v_rcp_f32 %0, %1" : "=v"(r) : "v"(x)); return r;
}

// ---- prep: weight pack + W2Wg + bg' + emb->bf16 + zero summed + zero cnt ----------
// Weight fragment layout (verified R3): frag f, lane l, elem j -> W[k][n],
// k = kc*32 + (l>>4)*8 + j, n = nt*16 + (l&15).
// f in [0,16): W1; [16,24): W2; [24,32): (W2@Wg)*log2e.
// NOTE: histogram branch removed (moved into main kernel); cnt zeroing added here
// (legal now: nothing in prep writes cnt concurrently).

__global__ void prep_kernel(const float* __restrict__ W1, const float* __restrict__ W2,
                            const float* __restrict__ Wg,
                            const float* __restrict__ b2, const float* __restrict__ bg,
                            const float* __restrict__ emb,
                            ushort_t* __restrict__ wpack, float* __restrict__ bgp,
                            ushort_t* __restrict__ emb_bf, int* __restrict__ cnt,
                            float* __restrict__ summed,
                            int total_emb, int N, int cvt_blocks, int zblocks) {
    const int bid = blockIdx.x;
    if (bid < 64) {                              // 64*256 == NFRAG*512: weight packing
        const int t = bid * 256 + threadIdx.x;
        const int f = t >> 9;
        const int l = (t >> 3) & 63;
        const int j = t & 7;
        const int k = ((f < 16) ? (f & 3) : ((f - 16) & 1)) * 32 + (l >> 4) * 8 + j;
        const int n = ((f < 16) ? (f >> 2) : (((f & 7)) >> 1)) * 16 + (l & 15);
        float v;
        if (f < 16)      v = W1[k * 64 + n];
        else if (f < 24) v = W2[k * 64 + n];
        else {                                   // (W2@Wg)[k][n] * log2(e)
            float s = 0.f;
            const float* wr = W2 + k * 64;
#pragma unroll 8
            for (int m = 0; m < 64; ++m) s += wr[m] * Wg[m * 64 + n];
            v = s * LOG2E;
        }
        wpack[t] = f2bf(v);
    } else if (bid < 64 + cvt_blocks) {          // node_emb -> bf16
        const int idx  = (bid - 64) * 256 + threadIdx.x;
        const int base = idx * 8;
        if (base < total_emb) {
            const float4 a = *(const float4*)(emb + base);
            const float4 b = *(const float4*)(emb + base + 4);
            u16x8 p;
            p[0]=f2bf(a.x); p[1]=f2bf(a.y); p[2]=f2bf(a.z); p[3]=f2bf(a.w);
            p[4]=f2bf(b.x); p[5]=f2bf(b.y); p[6]=f2bf(b.z); p[7]=f2bf(b.w);
            *(u16x8*)(emb_bf + base) = p;
        }
    } else if (bid == 64 + cvt_blocks) {         // bg' = (b2@Wg + bg) * log2(e)
        const int n = threadIdx.x;
        if (n < 64) {
            float s = bg[n];
#pragma unroll 8
            for (int m = 0; m < 64; ++m) s += b2[m] * Wg[m * 64 + n];
            bgp[n] = s * LOG2E;
        }
    } else if (bid < 65 + cvt_blocks + zblocks) {    // zero summed
        const int idx  = (bid - 65 - cvt_blocks) * 256 + threadIdx.x;
        const int base = idx * 4;
        if (base < total_emb)
            *(float4*)(summed + base) = (float4){0.f, 0.f, 0.f, 0.f};
    } else {                                     // zero cnt
        const int idx  = (bid - 65 - cvt_blocks - zblocks) * 256 + threadIdx.x;
        const int base = idx * 4;
        if (base + 3 < N) {
            *(int4*)(cnt + base) = (int4){0, 0, 0, 0};
        } else {
            for (int k = base; k < N; ++k) cnt[k] = 0;
        }
    }
}

// ---------------- fused MFMA MLP + per-edge atomic emit (barrier-free) -------------
// Wave w exclusively owns its 4352B slab + srcIds rows 16w..16w+15. All LDS
// dependencies are intra-wave (issue-order DS pipe + compiler lgkmcnt waits), so
// pair -> h reuse one slab with no __syncthreads.
// Emit: C-fragment row r is held by the 16 lanes of quad r>>2 (4 floats each, one
// per nt). Round i: every quad q emits edge-row 4q+i -> 4 unsafeAtomicAdd/lane into
// summed[src*64 + nt*16 + cn]; lane cn==0 bumps cnt[src]. Fire-and-forget.

__global__ __launch_bounds__(BLOCK, 8)
void edge_mlp_mfma(const ushort_t* __restrict__ emb_bf,   // [N][64] bf16
                   const int* __restrict__ ei,            // src[0..E), dst[E..2E)
                   const ushort_t* __restrict__ wpack,    // 32 packed B-frags
                   const float* __restrict__ b1, const float* __restrict__ b2,
                   const float* __restrict__ bgp,         // (b2@Wg + bg) * log2e
                   int*   __restrict__ cnt,               // per-node edge counts (out)
                   float* __restrict__ summed,            // [N][D] pre-zeroed (out)
                   int E)
{
    __shared__ char  slab[4][SLAB_B];    // 17408 B: per-wave pair then h
    __shared__ int   srcIds[TILE];

    const int tid = threadIdx.x;

    // ---- stage: 4 consecutive lanes cover one edge's 128B src + 128B dst rows ----
    {
        const int e = tid >> 2, q4 = tid & 3;     // e: edge slot 0..63, q4: quarter
        ushort_t* prow = (ushort_t*)&slab[e >> 4][(e & 15) * (PAIR_STR * 2)];
        const int ide = blockIdx.x * TILE + e;
        if (ide < E) {
            const int s  = ei[ide];
            const int dn = ei[E + ide];
            if (q4 == 0) srcIds[e] = s;
            const ushort_t* sr = emb_bf + (size_t)s  * D + q4 * 16;
            const ushort_t* dr = emb_bf + (size_t)dn * D + q4 * 16;
            *(u16x8*)&prow[q4 * 16]          = *(const u16x8*)sr;
            *(u16x8*)&prow[q4 * 16 + 8]      = *(const u16x8*)(sr + 8);
            *(u16x8*)&prow[64 + q4 * 16]     = *(const u16x8*)dr;
            *(u16x8*)&prow[64 + q4 * 16 + 8] = *(const u16x8*)(dr + 8);
        } else {
            if (q4 == 0) srcIds[e] = -1;
            const u16x8 z = {0,0,0,0,0,0,0,0};
            *(u16x8*)&prow[q4 * 16]          = z;
            *(u16x8*)&prow[q4 * 16 + 8]      = z;
            *(u16x8*)&prow[64 + q4 * 16]     = z;
            *(u16x8*)&prow[64 + q4 * 16 + 8] = z;
        }
    }

    const int w    = tid >> 6;           // wave id: owns slab[w] + rows 16w..16w+15
    const int ln   = tid & 63;
    const int quad = ln >> 4;
    const int cn   = ln & 15;
    ushort_t* pairW = (ushort_t*)slab[w];   // [16][136]
    ushort_t* hW    = (ushort_t*)slab[w];   // [16][72]  (overwrites pair after a1 reads)

    // ---- GEMM1: h = relu(pair @ W1 + b1), M=16 K=128 N=64 (kc-outer) ----
    f32x4 acc1[4];
#pragma unroll
    for (int nt = 0; nt < 4; ++nt) {
        const float b = b1[nt * 16 + cn];
        acc1[nt] = (f32x4){b, b, b, b};
    }
#pragma unroll
    for (int kc = 0; kc < 4; ++kc) {
        const bf16x8 a = *(const bf16x8*)&pairW[cn * PAIR_STR + kc * 32 + quad * 8];
#pragma unroll
        for (int nt = 0; nt < 4; ++nt) {
            const bf16x8 bf = *(const bf16x8*)(wpack + ((nt * 4 + kc) * 64 + ln) * 8);
            acc1[nt] = __builtin_amdgcn_mfma_f32_16x16x32_bf16(a, bf, acc1[nt], 0, 0, 0);
        }
    }
#pragma unroll
    for (int nt = 0; nt < 4; ++nt)
#pragma unroll
        for (int r = 0; r < 4; ++r)
            hW[(quad * 4 + r) * H_STR + nt * 16 + cn] = f2bf(fmaxf(acc1[nt][r], 0.f));

    // ---- GEMM2+3 fused (kc-outer): interaction = h@W2+b2 ; gate_pre = h@(W2Wg*log2e)+bg'
    f32x4 acc2[4], accg[4];
#pragma unroll
    for (int nt = 0; nt < 4; ++nt) {
        const float b  = b2 [nt * 16 + cn];
        const float bG = bgp[nt * 16 + cn];
        acc2[nt] = (f32x4){b, b, b, b};
        accg[nt] = (f32x4){bG, bG, bG, bG};
    }
#pragma unroll
    for (int kc = 0; kc < 2; ++kc) {
        const bf16x8 a = *(const bf16x8*)&hW[cn * H_STR + kc * 32 + quad * 8];
#pragma unroll
        for (int nt = 0; nt < 4; ++nt) {
            const bf16x8 bf2 = *(const bf16x8*)(wpack + ((16 + nt * 2 + kc) * 64 + ln) * 8);
            const bf16x8 bfg = *(const bf16x8*)(wpack + ((24 + nt * 2 + kc) * 64 + ln) * 8);
            acc2[nt] = __builtin_amdgcn_mfma_f32_16x16x32_bf16(a, bf2, acc2[nt], 0, 0, 0);
            accg[nt] = __builtin_amdgcn_mfma_f32_16x16x32_bf16(a, bfg, accg[nt], 0, 0, 0);
        }
    }

    // ---- gated = interaction * sigmoid(gate_pre); g[nt][r] for row 4*quad+r ----
    float g[4][4];
#pragma unroll
    for (int nt = 0; nt < 4; ++nt)
#pragma unroll
        for (int r = 0; r < 4; ++r) {
            const float ex = fexp2(-accg[nt][r]);
            g[nt][r] = acc2[nt][r] * frcp(1.0f + ex);
        }

    // ---- per-edge atomic emit: round i, quad q emits edge-row 4q+i ----
#pragma unroll
    for (int i = 0; i < 4; ++i) {
        const int s = srcIds[16 * w + 4 * quad + i];   // broadcast within quad
        if (s >= 0) {
            float* base = summed + (size_t)s * D + cn;
            unsafeAtomicAdd(base,      g[0][i]);
            unsafeAtomicAdd(base + 16, g[1][i]);
            unsafeAtomicAdd(base + 32, g[2][i]);
            unsafeAtomicAdd(base + 48, g[3][i]);
            if (cn == 0) atomicAdd(&cnt[s], 1);
        }
    }
}

// ---------------- finalize: pooled = summed * rcp(max(cnt,1)), in place -----------

__global__ void finalize_kernel(float* __restrict__ summed, const int* __restrict__ cnt,
                                int total_emb) {
    const int idx  = blockIdx.x * 256 + threadIdx.x;
    const int base = idx * 4;
    if (base < total_emb) {
        const int node = base >> 6;                    // 64 floats per node
        const float rc = frcp(fmaxf((float)cnt[node], 1.0f));
        float4 v = *(float4*)(summed + base);
        v.x *= rc; v.y *= rc; v.z *= rc; v.w *= rc;
        *(float4*)(summed + base) = v;
    }
}

extern "C" void kernel_launch(void* const* d_in, const int* in_sizes, int n_in,
                              void* d_out, int out_size, void* d_ws, size_t ws_size,
                              hipStream_t stream) {
    const float* node_emb   = (const float*)d_in[0];
    const int*   edge_index = (const int*)d_in[1];
    const float* W1 = (const float*)d_in[2];
    const float* b1 = (const float*)d_in[3];
    const float* W2 = (const float*)d_in[4];
    const float* b2 = (const float*)d_in[5];
    const float* Wg = (const float*)d_in[6];
    const float* bg = (const float*)d_in[7];

    const int N = in_sizes[0] / D;
    const int E = in_sizes[1] / 2;
    const int total_emb = N * D;

    // ws layout (shrunk -- sort pipeline deleted):
    // cnt[N] | bgp[64 f32] | wpack[16K bf16] | emb_bf[N*64 bf16]
    int* cnt    = (int*)d_ws;
    float* bgp  = (float*)(cnt + N);
    ushort_t* wpack  = (ushort_t*)(bgp + 64);
    ushort_t* emb_bf = wpack + NFRAG * 512;

    float* summed = (float*)d_out;

    const int cvt_blocks = (total_emb / 8 + 255) / 256;
    const int zblocks    = (total_emb / 4 + 255) / 256;
    const int cblocks    = ((N + 3) / 4 + 255) / 256;
    prep_kernel<<<65 + cvt_blocks + zblocks + cblocks, 256, 0, stream>>>(
        W1, W2, Wg, b2, bg, node_emb,
        wpack, bgp, emb_bf, cnt, summed, total_emb, N, cvt_blocks, zblocks);

    const int ntiles = (E + TILE - 1) / TILE;
    edge_mlp_mfma<<<ntiles, BLOCK, 0, stream>>>(emb_bf, edge_index, wpack,
                                                b1, b2, bgp, cnt, summed, E);

    finalize_kernel<<<zblocks, 256, 0, stream>>>(summed, cnt, total_emb);
}